// Round 12
// baseline (401.228 us; speedup 1.0000x reference)
//
#include <hip/hip_runtime.h>
#include <hip/hip_bf16.h>
#include <hip/hip_fp16.h>

#define D 64
#define GRAPHS 128

using bf16x8 = __attribute__((ext_vector_type(8))) short;   // 8 bf16 (4 VGPRs)
using f32x4  = __attribute__((ext_vector_type(4))) float;

// H layout: 8 dense planes, plane(p,s) = features [p*32,(p+1)*32) of hop-slot s.
// addr(p,s,n,f') = ((p*4+s)*N + n)*32 + f'
// One gather PHASE (separate dispatch!) touches ONE 3.2 MB plane -> fits 4 MiB
// per-XCD L2 -> deg~16 reuse becomes L2 hits. (R10 ran both phases co-resident
// in one dispatch and thrashed; serialization is the fix.)

__device__ __forceinline__ float bf2f(unsigned short u) {
    return __uint_as_float(((unsigned)u) << 16);
}
__device__ __forceinline__ unsigned short f2bf(float f) {
    unsigned u = __float_as_uint(f);
    unsigned r = (u + 0x7FFFu + ((u >> 16) & 1u)) >> 16;   // RNE
    return (unsigned short)r;
}

// ---------------- pass 1a: degree histogram + slot record ----------------

__global__ void deg_kernel(const int* __restrict__ dst, int* __restrict__ deg,
                           int* __restrict__ pos, int E) {
    int e = blockIdx.x * blockDim.x + threadIdx.x;
    if (e < E) pos[e] = atomicAdd(&deg[dst[e]], 1);
}

// ---------------- pass 1b: W -> MFMA B-frags + x -> bf16 planes (p, slot 0) ----------------

__global__ void prep_kernel(const float* __restrict__ W0, const float* __restrict__ W1,
                            unsigned short* __restrict__ WF0, unsigned short* __restrict__ WF1,
                            const float* __restrict__ x, unsigned short* __restrict__ H,
                            int N, int total) {
    int b = blockIdx.x;
    if (b < 128) {
        // Wfrag[kt][ct][lane][j]: B[k= kt*32 + (lane>>4)*8 + j][n= ct*16 + (lane&15)]
        int idx = b * 256 + threadIdx.x;   // 32768 = 2 * 16384
        int i = idx & 16383;
        int j = i & 7, lane = (i >> 3) & 63, ct = (i >> 9) & 3, kt = i >> 11;
        int n = ct * 16 + (lane & 15);
        int k = kt * 32 + (lane >> 4) * 8 + j;
        if (idx < 16384) WF0[i] = f2bf(W0[k * 64 + n]);
        else             WF1[i] = f2bf(W1[k * 64 + n]);
    } else {
        int i = (b - 128) * 256 + threadIdx.x;
        if (i < total) {
            int n = i >> 6, f = i & 63;
            int p = f >> 5, fp = f & 31;
            H[((size_t)(p * 4 + 0) * N + n) * 32 + fp] = f2bf(x[i]);
        }
    }
}

// ---------------- pass 2: dinv + pdeg + single-pass scan (atomic ticket) + pad fill ----------------

__global__ void scan_all_kernel(const int* __restrict__ deg, float* __restrict__ dinv,
                                int* __restrict__ pdeg, int* __restrict__ rowstart,
                                unsigned int* __restrict__ ep, int* __restrict__ total, int N) {
    __shared__ int s[256];
    __shared__ int base_sh;
    int i = blockIdx.x * 256 + threadIdx.x;
    int d = 0, p = 0;
    if (i < N) {
        d = deg[i];
        dinv[i] = d > 0 ? rsqrtf((float)d) : 0.0f;
        p = (d + 7) & ~7;
        pdeg[i] = p;
    }
    s[threadIdx.x] = p;
    __syncthreads();
    for (int st = 1; st < 256; st <<= 1) {
        int add = (threadIdx.x >= st) ? s[threadIdx.x - st] : 0;
        __syncthreads();
        s[threadIdx.x] += add;
        __syncthreads();
    }
    if (threadIdx.x == 255) base_sh = atomicAdd(total, s[255]);
    __syncthreads();
    if (i < N) {
        int excl = base_sh + s[threadIdx.x] - p;
        rowstart[i] = excl;
        for (int q = excl + d; q < excl + p; ++q) ep[q] = 0u;   // zero-weight pad
    }
}

// ---------------- pass 3: atomic-free scatter ----------------
// ep entry = (src u16) | (fp16(dinv[src]) << 16); dinv[dst] applied in gather.

__global__ void scatter_kernel(const int* __restrict__ src, const int* __restrict__ dst,
                               const int* __restrict__ pos, const float* __restrict__ dinv,
                               const int* __restrict__ rowstart, unsigned int* __restrict__ ep, int E) {
    int e = blockIdx.x * blockDim.x + threadIdx.x;
    if (e < E) {
        int d = dst[e], s = src[e];
        unsigned short wu = __half_as_ushort(__float2half(dinv[s]));
        ep[rowstart[d] + pos[e]] = (unsigned)s | ((unsigned)wu << 16);
    }
}

// ---------------- half-plane gather (ONE phase per dispatch -> 3.2 MB L2-resident) ----------------
// Wave per node: g=lane>>4 edge subgroup (4 edges/iter x 2 pipelined), u=lane&15
// -> ushort2 (2 feats/lane = 32 feats). ep nontemporal (streamed, read once per
// phase); out nontemporal store (written once, consumer refetches later).

#define GROWS 8   // 512 threads/block, 8 nodes/block

__global__ __launch_bounds__(512, 8)
void gather_kernel(const unsigned short* __restrict__ H, int s_in, int s_out, int phase,
                   const int* __restrict__ rowstart, const int* __restrict__ pdeg,
                   const float* __restrict__ dinv, const unsigned int* __restrict__ ep,
                   unsigned short* __restrict__ Hout, int N) {
    int wid = blockIdx.x * GROWS + (threadIdx.x >> 6);
    if (wid >= N) return;
    int lane = threadIdx.x & 63;
    int g = lane >> 4;           // edge subgroup 0..3
    int u = lane & 15;           // feature-pair -> feats u*2, u*2+1

    const unsigned short* in = H    + (size_t)(phase * 4 + s_in)  * N * 32;
    unsigned short*      out = Hout + (size_t)(phase * 4 + s_out) * N * 32;

    int start = __builtin_amdgcn_readfirstlane(rowstart[wid]);
    int cnt   = __builtin_amdgcn_readfirstlane(pdeg[wid]);    // multiple of 8
    float dd  = dinv[wid];                                    // wave-uniform

    float a0 = 0.f, a1 = 0.f, b0 = 0.f, b1 = 0.f;
    unsigned eA = 0, eB = 0;
    if (cnt > 0) {
        eA = __builtin_nontemporal_load(&ep[start + g]);
        eB = __builtin_nontemporal_load(&ep[start + 4 + g]);
    }
    for (int i = 0; i < cnt; i += 8) {
        unsigned cA = eA, cB = eB;
        if (i + 8 < cnt) {
            eA = __builtin_nontemporal_load(&ep[start + i + 8 + g]);
            eB = __builtin_nontemporal_load(&ep[start + i + 12 + g]);
        }
        unsigned rA = *(const unsigned*)(in + (size_t)(cA & 0xFFFFu) * 32 + u * 2);
        unsigned rB = *(const unsigned*)(in + (size_t)(cB & 0xFFFFu) * 32 + u * 2);
        float wA = __half2float(__ushort_as_half((unsigned short)(cA >> 16)));
        float wB = __half2float(__ushort_as_half((unsigned short)(cB >> 16)));
        a0 = fmaf(wA, bf2f((unsigned short)rA), a0);
        a1 = fmaf(wA, bf2f((unsigned short)(rA >> 16)), a1);
        b0 = fmaf(wB, bf2f((unsigned short)rB), b0);
        b1 = fmaf(wB, bf2f((unsigned short)(rB >> 16)), b1);
    }
    a0 += b0; a1 += b1;
    a0 += __shfl_xor(a0, 16, 64); a0 += __shfl_xor(a0, 32, 64);
    a1 += __shfl_xor(a1, 16, 64); a1 += __shfl_xor(a1, 32, 64);
    if (g == 0) {
        unsigned pk = (unsigned)f2bf(a0 * dd) | ((unsigned)f2bf(a1 * dd) << 16);
        __builtin_nontemporal_store(pk, (unsigned*)(out + (size_t)wid * 32 + u * 2));
    }
}

// ---------------- layer projection: C[N x 64] = H[N x 256] @ Wflat[256 x 64] ----------------
// A chunk kt -> plane (p=kt&1, s=kt>>1), 16 B contiguous.
// MODE 2: H2 planes (p,0) = prelu(C+b); block 0 inits out[]=bout.
// MODE 3: fused pool via LDS bins (batch sorted).

template<int MODE>
__global__ __launch_bounds__(256, 4)
void tag_gemm_kernel(const unsigned short* __restrict__ H,
                     const unsigned short* __restrict__ Wfrag,
                     const float* __restrict__ bias, const float* __restrict__ alpha,
                     const float* __restrict__ Wout, const int* __restrict__ batch,
                     const float* __restrict__ bout,
                     unsigned short* __restrict__ H2, float* __restrict__ outp, int N) {
    __shared__ float bins[GRAPHS];
    if (MODE == 3) {
        if (threadIdx.x < GRAPHS) bins[threadIdx.x] = 0.0f;
        __syncthreads();
    }
    if (MODE == 2) {
        if (blockIdx.x == 0 && threadIdx.x < GRAPHS) outp[threadIdx.x] = bout[0];
    }

    int w = threadIdx.x >> 6, lane = threadIdx.x & 63;
    int m = lane & 15, quad = lane >> 4;
    int rowbase = blockIdx.x * 64 + w * 16;
    int arow = min(rowbase + m, N - 1);

    f32x4 acc0 = {0.f, 0.f, 0.f, 0.f}, acc1 = acc0, acc2 = acc0, acc3 = acc0;
#pragma unroll
    for (int kt = 0; kt < 8; ++kt) {
        int p = kt & 1, s = kt >> 1;
        bf16x8 A = *(const bf16x8*)(H + ((size_t)(p * 4 + s) * N + arow) * 32 + quad * 8);
        const unsigned short* wf = Wfrag + ((size_t)(kt * 4) * 64 + lane) * 8;
        bf16x8 B0 = *(const bf16x8*)(wf + 0 * 64 * 8);
        bf16x8 B1 = *(const bf16x8*)(wf + 1 * 64 * 8);
        bf16x8 B2 = *(const bf16x8*)(wf + 2 * 64 * 8);
        bf16x8 B3 = *(const bf16x8*)(wf + 3 * 64 * 8);
        acc0 = __builtin_amdgcn_mfma_f32_16x16x32_bf16(A, B0, acc0, 0, 0, 0);
        acc1 = __builtin_amdgcn_mfma_f32_16x16x32_bf16(A, B1, acc1, 0, 0, 0);
        acc2 = __builtin_amdgcn_mfma_f32_16x16x32_bf16(A, B2, acc2, 0, 0, 0);
        acc3 = __builtin_amdgcn_mfma_f32_16x16x32_bf16(A, B3, acc3, 0, 0, 0);
    }

    float al = alpha[0];
    f32x4 accs[4] = {acc0, acc1, acc2, acc3};
    if (MODE == 2) {
#pragma unroll
        for (int ct = 0; ct < 4; ++ct) {
            int col = ct * 16 + m;
            int p = col >> 5, fp = col & 31;
            float b = bias[col];
#pragma unroll
            for (int r = 0; r < 4; ++r) {
                int row = rowbase + quad * 4 + r;
                if (row < N) {
                    float v = accs[ct][r] + b;
                    v = v >= 0.f ? v : al * v;
                    H2[((size_t)(p * 4 + 0) * N + row) * 32 + fp] = f2bf(v);
                }
            }
        }
    } else {
        float rv0 = 0.f, rv1 = 0.f, rv2 = 0.f, rv3 = 0.f;
#pragma unroll
        for (int ct = 0; ct < 4; ++ct) {
            int col = ct * 16 + m;
            float b = bias[col], wo = Wout[col];
            float v;
            v = accs[ct][0] + b; v = v >= 0.f ? v : al * v; rv0 = fmaf(v, wo, rv0);
            v = accs[ct][1] + b; v = v >= 0.f ? v : al * v; rv1 = fmaf(v, wo, rv1);
            v = accs[ct][2] + b; v = v >= 0.f ? v : al * v; rv2 = fmaf(v, wo, rv2);
            v = accs[ct][3] + b; v = v >= 0.f ? v : al * v; rv3 = fmaf(v, wo, rv3);
        }
        float rv[4] = {rv0, rv1, rv2, rv3};
#pragma unroll
        for (int r = 0; r < 4; ++r) {
            float v = rv[r];
            v += __shfl_xor(v, 8, 16);
            v += __shfl_xor(v, 4, 16);
            v += __shfl_xor(v, 2, 16);
            v += __shfl_xor(v, 1, 16);
            int row = rowbase + quad * 4 + r;
            if (m == 0 && row < N) atomicAdd(&bins[batch[row]], v);
        }
        __syncthreads();
        if (threadIdx.x < GRAPHS) {
            float bv = bins[threadIdx.x];
            if (bv != 0.0f) atomicAdd(&outp[threadIdx.x], bv);
        }
    }
}

extern "C" void kernel_launch(void* const* d_in, const int* in_sizes, int n_in,
                              void* d_out, int out_size, void* d_ws, size_t ws_size,
                              hipStream_t stream) {
    const float* x     = (const float*)d_in[0];
    const int*   ei    = (const int*)d_in[1];
    const int*   batch = (const int*)d_in[2];
    const float* W0    = (const float*)d_in[3];
    const float* b0    = (const float*)d_in[4];
    const float* W1    = (const float*)d_in[5];
    const float* b1    = (const float*)d_in[6];
    const float* a0    = (const float*)d_in[7];
    const float* a1    = (const float*)d_in[8];
    const float* Wout  = (const float*)d_in[9];
    const float* bout  = (const float*)d_in[10];

    const int N = in_sizes[0] / D;
    const int E = in_sizes[1] / 2;
    const int* src = ei;
    const int* dst = ei + E;

    size_t off = 0;
    auto alloc = [&](size_t bytes) -> void* {
        void* p = (char*)d_ws + off;
        off = (off + bytes + 255) & ~(size_t)255;
        return p;
    };
    const int NB = (N + 255) / 256;
    int*   deg      = (int*)alloc((size_t)(N + 1) * 4);   // deg[N] = scan ticket counter
    int*   pdeg     = (int*)alloc((size_t)N * 4);
    int*   rowstart = (int*)alloc((size_t)N * 4);
    float* dinv     = (float*)alloc((size_t)N * 4);
    int*   pos      = (int*)alloc((size_t)E * 4);
    unsigned int* epack = (unsigned int*)alloc(((size_t)E + 8ull * N) * 4);  // padded CSR, 4 B
    unsigned short* HA = (unsigned short*)alloc((size_t)N * 256 * 2);        // 8 planes x [N][32]
    unsigned short* HB = (unsigned short*)alloc((size_t)N * 256 * 2);
    unsigned short* WF0 = (unsigned short*)alloc(16384 * 2);
    unsigned short* WF1 = (unsigned short*)alloc(16384 * 2);

    const int EB = (E + 255) / 256;
    const int NT = (N * D + 255) / 256;
    const int NG = (N + GROWS - 1) / GROWS;      // gather blocks (512 thr)
    const int NM = (N + 63) / 64;                // gemm blocks (256 thr)

    // --- CSR build + prep ---
    hipMemsetAsync(deg, 0, (size_t)(N + 1) * 4, stream);
    deg_kernel<<<EB, 256, 0, stream>>>(dst, deg, pos, E);
    prep_kernel<<<128 + NT, 256, 0, stream>>>(W0, W1, WF0, WF1, x, HA, N, N * D);
    scan_all_kernel<<<NB, 256, 0, stream>>>(deg, dinv, pdeg, rowstart, epack, deg + N, N);
    scatter_kernel<<<EB, 256, 0, stream>>>(src, dst, pos, dinv, rowstart, epack, E);

    // --- layer 0: 3 hops x 2 serialized half-plane gathers, fused GEMM -> HB planes (p,0) ---
    for (int hop = 0; hop < 3; ++hop) {
        gather_kernel<<<NG, 512, 0, stream>>>(HA, hop, hop + 1, 0, rowstart, pdeg, dinv, epack, HA, N);
        gather_kernel<<<NG, 512, 0, stream>>>(HA, hop, hop + 1, 1, rowstart, pdeg, dinv, epack, HA, N);
    }
    tag_gemm_kernel<2><<<NM, 256, 0, stream>>>(HA, WF0, b0, a0, nullptr, nullptr, bout,
                                               HB, (float*)d_out, N);

    // --- layer 1: same, fused GEMM+pool -> out ---
    for (int hop = 0; hop < 3; ++hop) {
        gather_kernel<<<NG, 512, 0, stream>>>(HB, hop, hop + 1, 0, rowstart, pdeg, dinv, epack, HB, N);
        gather_kernel<<<NG, 512, 0, stream>>>(HB, hop, hop + 1, 1, rowstart, pdeg, dinv, epack, HB, N);
    }
    tag_gemm_kernel<3><<<NM, 256, 0, stream>>>(HB, WF1, b1, a1, Wout, batch, bout,
                                               nullptr, (float*)d_out, N);
}

// Round 14
// 284.936 us; speedup vs baseline: 1.4081x; 1.4081x over previous
//
#include <hip/hip_runtime.h>
#include <hip/hip_bf16.h>
#include <hip/hip_fp16.h>

#define D 64
#define GRAPHS 128

using bf16x8 = __attribute__((ext_vector_type(8))) short;   // 8 bf16 (4 VGPRs)
using f32x4  = __attribute__((ext_vector_type(4))) float;

// ---------------- small helpers ----------------

__device__ __forceinline__ float bf2f(unsigned short u) {
    return __uint_as_float(((unsigned)u) << 16);
}
__device__ __forceinline__ unsigned short f2bf(float f) {
    unsigned u = __float_as_uint(f);
    unsigned r = (u + 0x7FFFu + ((u >> 16) & 1u)) >> 16;   // RNE
    return (unsigned short)r;
}

// ---------------- pass 1: degree histogram + slot record, fused with W/x prep ----------------
// ep entry = (src u16) | (fp16(dinv[src]) << 16)  -- dinv[dst] factored out (applied in gather).

__global__ void deg_prep_kernel(const int* __restrict__ dst, int* __restrict__ deg,
                                int* __restrict__ pos, int E, int EB,
                                const float* __restrict__ W0, const float* __restrict__ W1,
                                unsigned short* __restrict__ WF0, unsigned short* __restrict__ WF1,
                                const float* __restrict__ x, unsigned short* __restrict__ H, int total) {
    int b = blockIdx.x;
    if (b < EB) {
        int e = b * 256 + threadIdx.x;
        if (e < E) pos[e] = atomicAdd(&deg[dst[e]], 1);
    } else if (b < EB + 128) {
        // Wfrag[kt][ct][lane][j]: B[k= kt*32 + (lane>>4)*8 + j][n= ct*16 + (lane&15)]
        int idx = (b - EB) * 256 + threadIdx.x;   // 32768 = 2 * 16384
        int i = idx & 16383;
        int j = i & 7, lane = (i >> 3) & 63, ct = (i >> 9) & 3, kt = i >> 11;
        int n = ct * 16 + (lane & 15);
        int k = kt * 32 + (lane >> 4) * 8 + j;
        if (idx < 16384) WF0[i] = f2bf(W0[k * 64 + n]);
        else             WF1[i] = f2bf(W1[k * 64 + n]);
    } else {
        int i = (b - EB - 128) * 256 + threadIdx.x;
        if (i < total) {
            int n = i >> 6, f = i & 63;
            H[(size_t)n * 256 + f] = f2bf(x[i]);
        }
    }
}

// ---------------- pass 2: dinv + pdeg + single-pass scan (atomic block ticket) + pad fill ----------------
// CSR row placement order is block-arbitrary but consistent within a replay -- harmless.

__global__ void scan_all_kernel(const int* __restrict__ deg, float* __restrict__ dinv,
                                int* __restrict__ pdeg, int* __restrict__ rowstart,
                                unsigned int* __restrict__ ep, int* __restrict__ total, int N) {
    __shared__ int s[256];
    __shared__ int base_sh;
    int i = blockIdx.x * 256 + threadIdx.x;
    int d = 0, p = 0;
    if (i < N) {
        d = deg[i];
        dinv[i] = d > 0 ? rsqrtf((float)d) : 0.0f;
        p = (d + 7) & ~7;
        pdeg[i] = p;
    }
    s[threadIdx.x] = p;
    __syncthreads();
    for (int st = 1; st < 256; st <<= 1) {
        int add = (threadIdx.x >= st) ? s[threadIdx.x - st] : 0;
        __syncthreads();
        s[threadIdx.x] += add;
        __syncthreads();
    }
    if (threadIdx.x == 255) base_sh = atomicAdd(total, s[255]);
    __syncthreads();
    if (i < N) {
        int excl = base_sh + s[threadIdx.x] - p;
        rowstart[i] = excl;
        for (int q = excl + d; q < excl + p; ++q) ep[q] = 0u;   // zero-weight pad
    }
}

// ---------------- pass 3: atomic-free scatter into padded CSR ----------------

__global__ void scatter_kernel(const int* __restrict__ src, const int* __restrict__ dst,
                               const int* __restrict__ pos, const float* __restrict__ dinv,
                               const int* __restrict__ rowstart, unsigned int* __restrict__ ep, int E) {
    int e = blockIdx.x * blockDim.x + threadIdx.x;
    if (e < E) {
        int d = dst[e], s = src[e];
        unsigned short wu = __half_as_ushort(__float2half(dinv[s]));
        ep[rowstart[d] + pos[e]] = (unsigned)s | ((unsigned)wu << 16);
    }
}

// ---------------- pure gather: out_row = dinv[dst] * sum_e dinv[src_e] * in_row[src_e] ----------------
// Wave per dst node. 16 lanes per edge (ushort4 = 4 features/lane, full 128 B row line);
// ep entries 4 B; next iteration's ep words prefetched before current row FMAs.

#define GROWS 8   // 512 threads/block, 8 nodes/block

__global__ __launch_bounds__(512, 8)
void gather_kernel(const unsigned short* __restrict__ in,   // H + slot_in*64
                   unsigned short* __restrict__ out,        // H + slot_out*64
                   const int* __restrict__ rowstart, const int* __restrict__ pdeg,
                   const float* __restrict__ dinv, const unsigned int* __restrict__ ep, int N) {
    int wid = blockIdx.x * GROWS + (threadIdx.x >> 6);
    if (wid >= N) return;
    int lane = threadIdx.x & 63;
    int g  = lane >> 4;          // edge subgroup 0..3
    int fl = (lane & 15) * 4;    // feature base (4 features per lane)

    int start = __builtin_amdgcn_readfirstlane(rowstart[wid]);
    int cnt   = __builtin_amdgcn_readfirstlane(pdeg[wid]);    // multiple of 8
    float dd  = dinv[wid];                                    // wave-uniform

    float a0 = 0.f, a1 = 0.f, a2 = 0.f, a3 = 0.f;
    float b0 = 0.f, b1 = 0.f, b2 = 0.f, b3 = 0.f;
    unsigned eA = 0, eB = 0;
    if (cnt > 0) { eA = ep[start + g]; eB = ep[start + 4 + g]; }
    for (int i = 0; i < cnt; i += 8) {
        unsigned cA = eA, cB = eB;
        if (i + 8 < cnt) { eA = ep[start + i + 8 + g]; eB = ep[start + i + 12 + g]; }
        ushort4 rA = *(const ushort4*)(in + (size_t)(cA & 0xFFFFu) * 256 + fl);
        ushort4 rB = *(const ushort4*)(in + (size_t)(cB & 0xFFFFu) * 256 + fl);
        float wA = __half2float(__ushort_as_half((unsigned short)(cA >> 16)));
        float wB = __half2float(__ushort_as_half((unsigned short)(cB >> 16)));
        a0 = fmaf(wA, bf2f(rA.x), a0);
        a1 = fmaf(wA, bf2f(rA.y), a1);
        a2 = fmaf(wA, bf2f(rA.z), a2);
        a3 = fmaf(wA, bf2f(rA.w), a3);
        b0 = fmaf(wB, bf2f(rB.x), b0);
        b1 = fmaf(wB, bf2f(rB.y), b1);
        b2 = fmaf(wB, bf2f(rB.z), b2);
        b3 = fmaf(wB, bf2f(rB.w), b3);
    }
    a0 += b0; a1 += b1; a2 += b2; a3 += b3;
    a0 += __shfl_xor(a0, 16, 64); a0 += __shfl_xor(a0, 32, 64);
    a1 += __shfl_xor(a1, 16, 64); a1 += __shfl_xor(a1, 32, 64);
    a2 += __shfl_xor(a2, 16, 64); a2 += __shfl_xor(a2, 32, 64);
    a3 += __shfl_xor(a3, 16, 64); a3 += __shfl_xor(a3, 32, 64);
    if (g == 0) {
        ushort4 pk;
        pk.x = f2bf(a0 * dd); pk.y = f2bf(a1 * dd); pk.z = f2bf(a2 * dd); pk.w = f2bf(a3 * dd);
        *(ushort4*)(out + (size_t)wid * 256 + fl) = pk;
    }
}

// ---------------- layer projection: C[N x 64] = H[N x 256] @ Wflat[256 x 64] ----------------
// MODE 2: H2 = prelu(C + b) (bf16); block 0 also initializes out[] = bout.
// MODE 3: pool fused: LDS bins per block (batch sorted -> ~2 graphs/block), few global atomics.

template<int MODE>
__global__ __launch_bounds__(256, 4)
void tag_gemm_kernel(const unsigned short* __restrict__ H,
                     const unsigned short* __restrict__ Wfrag,
                     const float* __restrict__ bias, const float* __restrict__ alpha,
                     const float* __restrict__ Wout, const int* __restrict__ batch,
                     const float* __restrict__ bout,
                     unsigned short* __restrict__ H2, float* __restrict__ outp, int N) {
    __shared__ float bins[GRAPHS];
    if (MODE == 3) {
        if (threadIdx.x < GRAPHS) bins[threadIdx.x] = 0.0f;
        __syncthreads();
    }
    if (MODE == 2) {
        if (blockIdx.x == 0 && threadIdx.x < GRAPHS) outp[threadIdx.x] = bout[0];
    }

    int w = threadIdx.x >> 6, lane = threadIdx.x & 63;
    int m = lane & 15, quad = lane >> 4;
    int rowbase = blockIdx.x * 64 + w * 16;
    int arow = rowbase + m;
    size_t aoff = (size_t)min(arow, N - 1) * 256 + quad * 8;

    f32x4 acc0 = {0.f, 0.f, 0.f, 0.f}, acc1 = acc0, acc2 = acc0, acc3 = acc0;
#pragma unroll
    for (int kt = 0; kt < 8; ++kt) {
        bf16x8 A = *(const bf16x8*)(H + aoff + kt * 32);
        const unsigned short* wf = Wfrag + ((size_t)(kt * 4) * 64 + lane) * 8;
        bf16x8 B0 = *(const bf16x8*)(wf + 0 * 64 * 8);
        bf16x8 B1 = *(const bf16x8*)(wf + 1 * 64 * 8);
        bf16x8 B2 = *(const bf16x8*)(wf + 2 * 64 * 8);
        bf16x8 B3 = *(const bf16x8*)(wf + 3 * 64 * 8);
        acc0 = __builtin_amdgcn_mfma_f32_16x16x32_bf16(A, B0, acc0, 0, 0, 0);
        acc1 = __builtin_amdgcn_mfma_f32_16x16x32_bf16(A, B1, acc1, 0, 0, 0);
        acc2 = __builtin_amdgcn_mfma_f32_16x16x32_bf16(A, B2, acc2, 0, 0, 0);
        acc3 = __builtin_amdgcn_mfma_f32_16x16x32_bf16(A, B3, acc3, 0, 0, 0);
    }

    float al = alpha[0];
    f32x4 accs[4] = {acc0, acc1, acc2, acc3};
    if (MODE == 2) {
#pragma unroll
        for (int ct = 0; ct < 4; ++ct) {
            int col = ct * 16 + m;
            float b = bias[col];
#pragma unroll
            for (int r = 0; r < 4; ++r) {
                int row = rowbase + quad * 4 + r;
                if (row < N) {
                    float v = accs[ct][r] + b;
                    v = v >= 0.f ? v : al * v;
                    H2[(size_t)row * 256 + col] = f2bf(v);
                }
            }
        }
    } else {
        float rv0 = 0.f, rv1 = 0.f, rv2 = 0.f, rv3 = 0.f;
#pragma unroll
        for (int ct = 0; ct < 4; ++ct) {
            int col = ct * 16 + m;
            float b = bias[col], wo = Wout[col];
            float v;
            v = accs[ct][0] + b; v = v >= 0.f ? v : al * v; rv0 = fmaf(v, wo, rv0);
            v = accs[ct][1] + b; v = v >= 0.f ? v : al * v; rv1 = fmaf(v, wo, rv1);
            v = accs[ct][2] + b; v = v >= 0.f ? v : al * v; rv2 = fmaf(v, wo, rv2);
            v = accs[ct][3] + b; v = v >= 0.f ? v : al * v; rv3 = fmaf(v, wo, rv3);
        }
        float rv[4] = {rv0, rv1, rv2, rv3};
#pragma unroll
        for (int r = 0; r < 4; ++r) {
            float v = rv[r];
            v += __shfl_xor(v, 8, 16);
            v += __shfl_xor(v, 4, 16);
            v += __shfl_xor(v, 2, 16);
            v += __shfl_xor(v, 1, 16);
            int row = rowbase + quad * 4 + r;
            if (m == 0 && row < N) atomicAdd(&bins[batch[row]], v);
        }
        __syncthreads();
        if (threadIdx.x < GRAPHS) {
            float bv = bins[threadIdx.x];
            if (bv != 0.0f) atomicAdd(&outp[threadIdx.x], bv);
        }
    }
}

extern "C" void kernel_launch(void* const* d_in, const int* in_sizes, int n_in,
                              void* d_out, int out_size, void* d_ws, size_t ws_size,
                              hipStream_t stream) {
    const float* x     = (const float*)d_in[0];
    const int*   ei    = (const int*)d_in[1];
    const int*   batch = (const int*)d_in[2];
    const float* W0    = (const float*)d_in[3];
    const float* b0    = (const float*)d_in[4];
    const float* W1    = (const float*)d_in[5];
    const float* b1    = (const float*)d_in[6];
    const float* a0    = (const float*)d_in[7];
    const float* a1    = (const float*)d_in[8];
    const float* Wout  = (const float*)d_in[9];
    const float* bout  = (const float*)d_in[10];

    const int N = in_sizes[0] / D;
    const int E = in_sizes[1] / 2;
    const int* src = ei;
    const int* dst = ei + E;

    size_t off = 0;
    auto alloc = [&](size_t bytes) -> void* {
        void* p = (char*)d_ws + off;
        off = (off + bytes + 255) & ~(size_t)255;
        return p;
    };
    const int NB = (N + 255) / 256;
    int*   deg      = (int*)alloc((size_t)(N + 1) * 4);   // deg[N] = scan ticket counter
    int*   pdeg     = (int*)alloc((size_t)N * 4);
    int*   rowstart = (int*)alloc((size_t)N * 4);
    float* dinv     = (float*)alloc((size_t)N * 4);
    int*   pos      = (int*)alloc((size_t)E * 4);
    unsigned int* epack = (unsigned int*)alloc(((size_t)E + 8ull * N) * 4);  // padded CSR, 4 B entries
    unsigned short* HA = (unsigned short*)alloc((size_t)N * 256 * 2);        // [N][4][64] bf16
    unsigned short* HB = (unsigned short*)alloc((size_t)N * 256 * 2);
    unsigned short* WF0 = (unsigned short*)alloc(16384 * 2);
    unsigned short* WF1 = (unsigned short*)alloc(16384 * 2);

    const int EB = (E + 255) / 256;
    const int NT = (N * D + 255) / 256;
    const int NG = (N + GROWS - 1) / GROWS;      // gather blocks (512 thr)
    const int NM = (N + 63) / 64;                // gemm blocks (256 thr)

    // --- CSR build + prep (3 kernels + memset) ---
    hipMemsetAsync(deg, 0, (size_t)(N + 1) * 4, stream);
    deg_prep_kernel<<<EB + 128 + NT, 256, 0, stream>>>(dst, deg, pos, E, EB,
                                                       W0, W1, WF0, WF1, x, HA, N * D);
    scan_all_kernel<<<NB, 256, 0, stream>>>(deg, dinv, pdeg, rowstart, epack, deg + N, N);
    scatter_kernel<<<EB, 256, 0, stream>>>(src, dst, pos, dinv, rowstart, epack, E);

    // --- layer 0: gathers fill HA slots 1..3, fused GEMM+bias+PReLU -> HB slot 0 (+ out init) ---
    gather_kernel<<<NG, 512, 0, stream>>>(HA + 0 * 64, HA + 1 * 64, rowstart, pdeg, dinv, epack, N);
    gather_kernel<<<NG, 512, 0, stream>>>(HA + 1 * 64, HA + 2 * 64, rowstart, pdeg, dinv, epack, N);
    gather_kernel<<<NG, 512, 0, stream>>>(HA + 2 * 64, HA + 3 * 64, rowstart, pdeg, dinv, epack, N);
    tag_gemm_kernel<2><<<NM, 256, 0, stream>>>(HA, WF0, b0, a0, nullptr, nullptr, bout,
                                               HB, (float*)d_out, N);

    // --- layer 1: gathers fill HB slots 1..3, fused GEMM+bias+PReLU+Wout-dot+pool -> out ---
    gather_kernel<<<NG, 512, 0, stream>>>(HB + 0 * 64, HB + 1 * 64, rowstart, pdeg, dinv, epack, N);
    gather_kernel<<<NG, 512, 0, stream>>>(HB + 1 * 64, HB + 2 * 64, rowstart, pdeg, dinv, epack, N);
    gather_kernel<<<NG, 512, 0, stream>>>(HB + 2 * 64, HB + 3 * 64, rowstart, pdeg, dinv, epack, N);
    tag_gemm_kernel<3><<<NM, 256, 0, stream>>>(HB, WF1, b1, a1, Wout, batch, bout,
                                               nullptr, (float*)d_out, N);
}